// Round 3
// baseline (1029.007 us; speedup 1.0000x reference)
//
#include <hip/hip_runtime.h>

typedef unsigned short u16;
typedef __bf16 bf16x8 __attribute__((ext_vector_type(8)));
typedef float f32x4 __attribute__((ext_vector_type(4)));

__device__ __forceinline__ float b2f(u16 u) {
  unsigned int x = ((unsigned int)u) << 16;
  float f;
  __builtin_memcpy(&f, &x, 4);
  return f;
}
__device__ __forceinline__ u16 f2b(float f) {
  unsigned int x;
  __builtin_memcpy(&x, &f, 4);
  unsigned int r = x + 0x7FFFu + ((x >> 16) & 1u);
  return (u16)(r >> 16);
}

// ---------------------------------------------------------------------------
// Input dtype sniffing: bf16 N(0,1) data never has exponent field >= 0x90;
// fp32 data read as u16 hits it ~44% of the time. flag=1 -> fp32 in/out.
// ---------------------------------------------------------------------------
__global__ __launch_bounds__(256) void detect_dtype(const u16* __restrict__ text,
                                                    int* __restrict__ flag) {
  __shared__ int red[4];
  const int t = threadIdx.x;
  int c = 0;
#pragma unroll
  for (int j = 0; j < 8; j++) {
    u16 u = text[t * 8 + j];
    int e = (u >> 7) & 0xFF;
    c += (e >= 0x90);
  }
#pragma unroll
  for (int off = 32; off; off >>= 1) c += __shfl_xor(c, off);
  if ((t & 63) == 0) red[t >> 6] = c;
  __syncthreads();
  if (t == 0) flag[0] = (red[0] + red[1] + red[2] + red[3] >= 16) ? 1 : 0;
}

// ---------------------------------------------------------------------------
// Canonicalize 8 inputs to bf16 workspace copies (either src dtype).
// ---------------------------------------------------------------------------
struct Cvt {
  const void* s;
  u16* d;
  int n;
};
struct Cvt8 {
  Cvt c[8];
};
__global__ __launch_bounds__(256) void convert8(Cvt8 args, const int* __restrict__ flag) {
  const Cvt cc = args.c[blockIdx.y];
  const int i8 = (blockIdx.x * 256 + threadIdx.x) * 8;
  if (i8 >= cc.n) return;
  u16 o[8];
  if (flag[0]) {
    const float* s = (const float*)cc.s + i8;
    float4 a = *(const float4*)s;
    float4 b = *(const float4*)(s + 4);
    o[0] = f2b(a.x); o[1] = f2b(a.y); o[2] = f2b(a.z); o[3] = f2b(a.w);
    o[4] = f2b(b.x); o[5] = f2b(b.y); o[6] = f2b(b.z); o[7] = f2b(b.w);
  } else {
    uint4 r = *(const uint4*)((const u16*)cc.s + i8);
    __builtin_memcpy(o, &r, 16);
  }
  uint4 pk;
  __builtin_memcpy(&pk, o, 16);
  *(uint4*)(cc.d + i8) = pk;
}

// ---------------------------------------------------------------------------
// NT GEMM: C[z][m][n] = scale * sum_k A[z][m][k] * B[z][n][k] (+ bias[n]).
// Output dtype: oflag ? (oflag[0] ? fp32 : bf16) : (OUT_BF16 ? bf16 : fp32).
// base/sC/ldc are ELEMENT offsets/strides (dtype-agnostic addressing).
// ---------------------------------------------------------------------------
template <int OUT_BF16, int ADD_BIAS>
__global__ __launch_bounds__(256) void gemm_nt(
    const u16* __restrict__ A, const u16* __restrict__ B, void* __restrict__ Cv,
    const u16* __restrict__ bias, int lda, int ldb, int ldc, int K,
    long sA, long sB, long sC, long base, float scale,
    const int* __restrict__ oflag) {
  __shared__ u16 As[128][40];
  __shared__ u16 Bs[128][40];
  const int t = threadIdx.x;
  A += (long)blockIdx.z * sA;
  B += (long)blockIdx.z * sB;
  const int bm = blockIdx.y * 128;
  const int bn = blockIdx.x * 128;
  const int lane = t & 63;
  const int wv = t >> 6;
  const int wm = (wv & 1) * 64;
  const int wn = (wv >> 1) * 64;
  const int lr = lane & 15;
  const int lq = lane >> 4;
  const int m0 = t >> 2;
  const int kc = (t & 3) << 3;
  const u16* pa0 = A + (size_t)(bm + m0) * lda + kc;
  const u16* pa1 = pa0 + (size_t)64 * lda;
  const u16* pb0 = B + (size_t)(bn + m0) * ldb + kc;
  const u16* pb1 = pb0 + (size_t)64 * ldb;

  f32x4 acc[4][4];
#pragma unroll
  for (int i = 0; i < 4; i++)
#pragma unroll
    for (int j = 0; j < 4; j++) acc[i][j] = (f32x4){0.f, 0.f, 0.f, 0.f};

  for (int k0 = 0; k0 < K; k0 += 32) {
    uint4 a0 = *(const uint4*)(pa0 + k0);
    uint4 a1 = *(const uint4*)(pa1 + k0);
    uint4 b0 = *(const uint4*)(pb0 + k0);
    uint4 b1 = *(const uint4*)(pb1 + k0);
    *(uint4*)&As[m0][kc] = a0;
    *(uint4*)&As[m0 + 64][kc] = a1;
    *(uint4*)&Bs[m0][kc] = b0;
    *(uint4*)&Bs[m0 + 64][kc] = b1;
    __syncthreads();
    bf16x8 af[4], bfr[4];
#pragma unroll
    for (int i = 0; i < 4; i++) af[i] = *(const bf16x8*)&As[wm + i * 16 + lr][lq * 8];
#pragma unroll
    for (int j = 0; j < 4; j++) bfr[j] = *(const bf16x8*)&Bs[wn + j * 16 + lr][lq * 8];
#pragma unroll
    for (int i = 0; i < 4; i++)
#pragma unroll
      for (int j = 0; j < 4; j++)
        acc[i][j] = __builtin_amdgcn_mfma_f32_16x16x32_bf16(af[i], bfr[j], acc[i][j], 0, 0, 0);
    __syncthreads();
  }

  int f32o = OUT_BF16 ? 0 : 1;
  if (oflag) f32o = oflag[0];
  u16* Cb = (u16*)Cv + base + (long)blockIdx.z * sC;
  float* Cf = (float*)Cv + base + (long)blockIdx.z * sC;
#pragma unroll
  for (int i = 0; i < 4; i++) {
    const int gm0 = bm + wm + i * 16 + lq * 4;
#pragma unroll
    for (int j = 0; j < 4; j++) {
      const int gn = bn + wn + j * 16 + lr;
      float bv = 0.f;
      if (ADD_BIAS) bv = b2f(bias[gn]);
#pragma unroll
      for (int r = 0; r < 4; r++) {
        float v = acc[i][j][r] * scale + bv;
        if (f32o)
          Cf[(size_t)(gm0 + r) * ldc + gn] = v;
        else
          Cb[(size_t)(gm0 + r) * ldc + gn] = f2b(v);
      }
    }
  }
}

// ---------------------------------------------------------------------------
// Flag-aware transpose of emb: in [z][384][1024] (fp32 or bf16) -> bf16
// out [z][1024][384]. 64x64 LDS tiles.
// ---------------------------------------------------------------------------
__global__ __launch_bounds__(256) void transpose_any(const void* __restrict__ in_,
                                                     u16* __restrict__ out,
                                                     const int* __restrict__ flag) {
  __shared__ u16 tile[64][72];
  const int t = threadIdx.x;
  const int z = blockIdx.z;
  const int r0 = blockIdx.y * 64;
  const int c0 = blockIdx.x * 64;
  const int isf32 = flag[0];
#pragma unroll
  for (int j = 0; j < 2; j++) {
    int idx = t + 256 * j;
    int r = idx >> 3, c8 = (idx & 7) << 3;
    u16 v[8];
    if (isf32) {
      const float* in = (const float*)in_ + (size_t)z * 393216 + (size_t)(r0 + r) * 1024 + c0 + c8;
      float4 a = *(const float4*)in;
      float4 b = *(const float4*)(in + 4);
      v[0] = f2b(a.x); v[1] = f2b(a.y); v[2] = f2b(a.z); v[3] = f2b(a.w);
      v[4] = f2b(b.x); v[5] = f2b(b.y); v[6] = f2b(b.z); v[7] = f2b(b.w);
    } else {
      const u16* in = (const u16*)in_ + (size_t)z * 393216 + (size_t)(r0 + r) * 1024 + c0 + c8;
      uint4 rr = *(const uint4*)in;
      __builtin_memcpy(v, &rr, 16);
    }
    __builtin_memcpy(&tile[r][c8], v, 16);
  }
  __syncthreads();
#pragma unroll
  for (int j = 0; j < 2; j++) {
    int idx = t + 256 * j;
    int c = idx >> 3, r8 = (idx & 7) << 3;
    u16 v[8];
#pragma unroll
    for (int jj = 0; jj < 8; jj++) v[jj] = tile[r8 + jj][c];
    uint4 pk;
    __builtin_memcpy(&pk, v, 16);
    *(uint4*)&out[(size_t)z * 393216 + (size_t)(c0 + c) * 384 + r0 + r8] = pk;
  }
}

// ---------------------------------------------------------------------------
// bf16 transpose: in [z][384][1024] -> out [z][1024][384]
// ---------------------------------------------------------------------------
__global__ __launch_bounds__(256) void transpose_bf16(const u16* __restrict__ in,
                                                      u16* __restrict__ out) {
  __shared__ u16 tile[64][72];
  const int t = threadIdx.x;
  in += (size_t)blockIdx.z * 393216;
  out += (size_t)blockIdx.z * 393216;
  const int r0 = blockIdx.y * 64;
  const int c0 = blockIdx.x * 64;
#pragma unroll
  for (int j = 0; j < 2; j++) {
    int idx = t + 256 * j;
    int r = idx >> 3, c8 = (idx & 7) << 3;
    *(uint4*)&tile[r][c8] = *(const uint4*)&in[(size_t)(r0 + r) * 1024 + c0 + c8];
  }
  __syncthreads();
#pragma unroll
  for (int j = 0; j < 2; j++) {
    int idx = t + 256 * j;
    int c = idx >> 3, r8 = (idx & 7) << 3;
    u16 v[8];
#pragma unroll
    for (int jj = 0; jj < 8; jj++) v[jj] = tile[r8 + jj][c];
    uint4 pk;
    __builtin_memcpy(&pk, v, 16);
    *(uint4*)&out[(size_t)(c0 + c) * 384 + r0 + r8] = pk;
  }
}

// ---------------------------------------------------------------------------
// In-place row L2-norm on bf16 [rows][1024] (torch F.normalize semantics)
// ---------------------------------------------------------------------------
__global__ __launch_bounds__(256) void l2norm_rows_bf16(u16* __restrict__ Q) {
  __shared__ float red[4];
  u16* row = Q + (size_t)blockIdx.x * 1024;
  const int t = threadIdx.x;
  uint2 r = *(const uint2*)(row + t * 4);
  u16 v[4];
  __builtin_memcpy(v, &r, 8);
  float f[4] = {b2f(v[0]), b2f(v[1]), b2f(v[2]), b2f(v[3])};
  float s = f[0] * f[0] + f[1] * f[1] + f[2] * f[2] + f[3] * f[3];
#pragma unroll
  for (int off = 32; off; off >>= 1) s += __shfl_xor(s, off);
  if ((t & 63) == 0) red[t >> 6] = s;
  __syncthreads();
  float tot = red[0] + red[1] + red[2] + red[3];
  float inv = 1.f / fmaxf(sqrtf(tot), 1e-12f);
  u16 o[4] = {f2b(f[0] * inv), f2b(f[1] * inv), f2b(f[2] * inv), f2b(f[3] * inv)};
  unsigned long long pk;
  __builtin_memcpy(&pk, o, 8);
  *(unsigned long long*)(row + t * 4) = pk;
}

// ---------------------------------------------------------------------------
// Grouped 3x3 conv (groups=192, 2 in / 2 out per group), SAME zero pad, 32x32.
// One block per (b, out_channel). z=0: k branch (fused row L2-norm). z=1: v.
// ---------------------------------------------------------------------------
__global__ __launch_bounds__(256) void gconv3x3(
    const u16* __restrict__ inK, const u16* __restrict__ inV,
    const u16* __restrict__ wK, const u16* __restrict__ wV,
    u16* __restrict__ outK, u16* __restrict__ outV) {
  __shared__ float p[2][1024];
  __shared__ float red[4];
  const int o = blockIdx.x;
  const int b = blockIdx.y;
  const int kv = blockIdx.z;
  const int t = threadIdx.x;
  const u16* in = (kv ? inV : inK) + ((size_t)b * 384 + (o & ~1)) * 1024;
  const u16* wp = (kv ? wV : wK) + o * 18;
  u16* out = (kv ? outV : outK) + ((size_t)b * 384 + o) * 1024;
  {
    uint2 ra = *(const uint2*)(in + t * 4);
    uint2 rb = *(const uint2*)(in + 1024 + t * 4);
    u16 va[4], vb[4];
    __builtin_memcpy(va, &ra, 8);
    __builtin_memcpy(vb, &rb, 8);
#pragma unroll
    for (int j = 0; j < 4; j++) {
      p[0][t * 4 + j] = b2f(va[j]);
      p[1][t * 4 + j] = b2f(vb[j]);
    }
  }
  float w[18];
#pragma unroll
  for (int j = 0; j < 18; j++) w[j] = b2f(wp[j]);
  __syncthreads();
  float o4[4];
#pragma unroll
  for (int ii = 0; ii < 4; ii++) {
    const int pidx = t + 256 * ii;
    const int y = pidx >> 5, x = pidx & 31;
    float acc = 0.f;
#pragma unroll
    for (int ch = 0; ch < 2; ch++)
#pragma unroll
      for (int dy = 0; dy < 3; dy++) {
        const int yy = y + dy - 1;
        if (yy < 0 || yy > 31) continue;
#pragma unroll
        for (int dx = 0; dx < 3; dx++) {
          const int xx = x + dx - 1;
          if (xx < 0 || xx > 31) continue;
          acc += w[ch * 9 + dy * 3 + dx] * p[ch][yy * 32 + xx];
        }
      }
    o4[ii] = acc;
  }
  float inv = 1.f;
  if (kv == 0) {
    float s = o4[0] * o4[0] + o4[1] * o4[1] + o4[2] * o4[2] + o4[3] * o4[3];
#pragma unroll
    for (int off = 32; off; off >>= 1) s += __shfl_xor(s, off);
    if ((t & 63) == 0) red[t >> 6] = s;
    __syncthreads();
    float tot = red[0] + red[1] + red[2] + red[3];
    inv = 1.f / fmaxf(sqrtf(tot), 1e-12f);
  }
#pragma unroll
  for (int ii = 0; ii < 4; ii++) out[t + 256 * ii] = f2b(o4[ii] * inv);
}

// ---------------------------------------------------------------------------
// Per-batch mean/rstd over the 384x384 score matrix (InstanceNorm2d stats)
// ---------------------------------------------------------------------------
__global__ __launch_bounds__(256) void stats16(const float* __restrict__ S,
                                               float* __restrict__ st) {
  __shared__ float rs[4], rq[4];
  const int b = blockIdx.x;
  const float4* p = (const float4*)(S + (size_t)b * 147456);
  float s = 0.f, q = 0.f;
  for (int i = threadIdx.x; i < 36864; i += 256) {
    float4 v = p[i];
    s += v.x + v.y + v.z + v.w;
    q += v.x * v.x + v.y * v.y + v.z * v.z + v.w * v.w;
  }
#pragma unroll
  for (int off = 32; off; off >>= 1) {
    s += __shfl_xor(s, off);
    q += __shfl_xor(q, off);
  }
  const int t = threadIdx.x;
  if ((t & 63) == 0) {
    rs[t >> 6] = s;
    rq[t >> 6] = q;
  }
  __syncthreads();
  if (t == 0) {
    float S1 = rs[0] + rs[1] + rs[2] + rs[3];
    float S2 = rq[0] + rq[1] + rq[2] + rq[3];
    float mean = S1 * (1.f / 147456.f);
    float var = S2 * (1.f / 147456.f) - mean * mean;
    st[0 + b * 2] = mean;
    st[1 + b * 2] = 1.f / sqrtf(var + 1e-5f);
  }
}

// ---------------------------------------------------------------------------
// Softmax over rows of 384 after inst-norm scale. One wave per row.
// ---------------------------------------------------------------------------
__global__ __launch_bounds__(256) void softmax384(const float* __restrict__ S,
                                                  const float* __restrict__ st,
                                                  u16* __restrict__ P) {
  const int row = blockIdx.x * 4 + (threadIdx.x >> 6);
  const int lane = threadIdx.x & 63;
  const int b = row / 384;
  const float rstd = st[b * 2 + 1];
  const float* x = S + (size_t)row * 384;
  float v[6];
#pragma unroll
  for (int j = 0; j < 6; j++) v[j] = x[lane + 64 * j] * rstd;
  float m = v[0];
#pragma unroll
  for (int j = 1; j < 6; j++) m = fmaxf(m, v[j]);
#pragma unroll
  for (int off = 32; off; off >>= 1) m = fmaxf(m, __shfl_xor(m, off));
  float s = 0.f;
#pragma unroll
  for (int j = 0; j < 6; j++) {
    v[j] = __expf(v[j] - m);
    s += v[j];
  }
#pragma unroll
  for (int off = 32; off; off >>= 1) s += __shfl_xor(s, off);
  const float inv = 1.f / s;
  u16* out = P + (size_t)row * 384;
#pragma unroll
  for (int j = 0; j < 6; j++) out[lane + 64 * j] = f2b(v[j] * inv);
}

// ---------------------------------------------------------------------------
// B=16, C=384, H=W=32, HW=1024, TEXT=768. Needs ~68.2 MB workspace.
// ---------------------------------------------------------------------------
extern "C" void kernel_launch(void* const* d_in, const int* in_sizes, int n_in,
                              void* d_out, int out_size, void* d_ws, size_t ws_size,
                              hipStream_t stream) {
  (void)in_sizes; (void)n_in; (void)out_size; (void)ws_size;
  char* ws = (char*)d_ws;

  int* flag = (int*)ws;
  float* st = (float*)(ws + 256);
  const size_t SLOT = 12582912;
  u16* q16 = (u16*)(ws + 1024);
  u16* s1 = (u16*)(ws + 1024 + SLOT);      // text16 -> xT -> k16 -> O16
  u16* s2 = (u16*)(ws + 1024 + 2 * SLOT);  // kpre16 -> vT -> OT
  u16* s3 = (u16*)(ws + 1024 + 3 * SLOT);  // vpre16 -> S(fp32)
  u16* s4 = (u16*)(ws + 1024 + 4 * SLOT);  // v16 -> P16
  char* cvt = ws + 1024 + 5 * SLOT;
  u16* wq16 = (u16*)cvt;
  u16* bq16 = (u16*)(cvt + 1572864);
  u16* mk16 = (u16*)(cvt + 1574912);
  u16* mv16 = (u16*)(cvt + 2754560);
  u16* kw16 = (u16*)(cvt + 3934208);
  u16* vw16 = (u16*)(cvt + 3989504);
  u16* po16 = (u16*)(cvt + 4044800);
  float* S = (float*)s3;
  u16* P16 = s4;

  const dim3 blk(256);
  const float scale = 0.05103103630798288f;  // 1/sqrt(384)

  detect_dtype<<<1, blk, 0, stream>>>((const u16*)d_in[4], flag);

  Cvt8 ca;
  const void* srcs[8] = {d_in[4], d_in[5], d_in[6], d_in[7],
                         d_in[8], d_in[9], d_in[10], d_in[11]};
  u16* dsts[8] = {s1, wq16, bq16, mk16, mv16, kw16, vw16, po16};
  const int ns[8] = {4718592, 786432, 1024, 589824, 589824, 27648, 27648, 589824};
  for (int j = 0; j < 8; j++) {
    ca.c[j].s = srcs[j];
    ca.c[j].d = dsts[j];
    ca.c[j].n = ns[j];
  }
  convert8<<<dim3(2304, 8, 1), blk, 0, stream>>>(ca, flag);

  // q = l2norm(text @ wq^T + bq): M=6144, N=1024, K=768
  gemm_nt<1, 1><<<dim3(8, 48, 1), blk, 0, stream>>>(s1, wq16, q16, bq16, 768, 768,
                                                    1024, 768, 0, 0, 0, 0, 1.f, nullptr);
  l2norm_rows_bf16<<<6144, blk, 0, stream>>>(q16);

  for (int i = 0; i < 4; i++) {
    transpose_any<<<dim3(16, 6, 16), blk, 0, stream>>>(d_in[i], s1, flag);
    gemm_nt<1, 0><<<dim3(8, 3, 16), blk, 0, stream>>>(mk16 + i * 147456, s1, s2,
                                                      nullptr, 384, 384, 1024, 384,
                                                      0, 393216, 393216, 0, 1.f, nullptr);
    gemm_nt<1, 0><<<dim3(8, 3, 16), blk, 0, stream>>>(mv16 + i * 147456, s1, s3,
                                                      nullptr, 384, 384, 1024, 384,
                                                      0, 393216, 393216, 0, 1.f, nullptr);
    gconv3x3<<<dim3(384, 16, 2), blk, 0, stream>>>(s2, s3, kw16 + i * 6912,
                                                   vw16 + i * 6912, s1, s4);
    transpose_bf16<<<dim3(16, 6, 16), blk, 0, stream>>>(s4, s2);
    gemm_nt<0, 0><<<dim3(3, 3, 16), blk, 0, stream>>>(q16, s1, S, nullptr, 1024,
                                                      1024, 384, 1024, 393216,
                                                      393216, 147456, 0, scale, nullptr);
    stats16<<<16, blk, 0, stream>>>(S, st);
    softmax384<<<1536, blk, 0, stream>>>(S, st, P16);
    gemm_nt<1, 0><<<dim3(8, 3, 16), blk, 0, stream>>>(P16, s2, s1, nullptr, 384,
                                                      384, 1024, 384, 147456,
                                                      393216, 393216, 0, 1.f, nullptr);
    transpose_bf16<<<dim3(16, 6, 16), blk, 0, stream>>>(s1, s2);
    // out_i = po_i @ O; dtype + element-addressed branch base chosen by flag
    gemm_nt<0, 0><<<dim3(8, 3, 16), blk, 0, stream>>>(
        po16 + i * 147456, s2, d_out, nullptr, 384, 384, 1024, 384, 0, 393216,
        393216, (long)i * 6291456, 1.f, flag);
  }
}

// Round 6
// 617.259 us; speedup vs baseline: 1.6671x; 1.6671x over previous
//
#include <hip/hip_runtime.h>

typedef unsigned short u16;
typedef __bf16 bf16x8 __attribute__((ext_vector_type(8)));
typedef float f32x4 __attribute__((ext_vector_type(4)));

__device__ __forceinline__ float b2f(u16 u) {
  unsigned int x = ((unsigned int)u) << 16;
  float f;
  __builtin_memcpy(&f, &x, 4);
  return f;
}
__device__ __forceinline__ u16 f2b(float f) {
  unsigned int x;
  __builtin_memcpy(&x, &f, 4);
  unsigned int r = x + 0x7FFFu + ((x >> 16) & 1u);
  return (u16)(r >> 16);
}

// ---------------------------------------------------------------------------
// Dtype sniff (bf16 N(0,1) never has exponent>=0x90; fp32-as-u16 does ~44%)
// + zero the stats accumulators (ws is 0xAA-poisoned before every call).
// ---------------------------------------------------------------------------
__global__ __launch_bounds__(256) void detect_dtype(const u16* __restrict__ text,
                                                    int* __restrict__ flag,
                                                    float* __restrict__ stats) {
  __shared__ int red[4];
  const int t = threadIdx.x;
  if (t < 128) stats[t] = 0.f;
  int c = 0;
#pragma unroll
  for (int j = 0; j < 8; j++) {
    u16 u = text[t * 8 + j];
    int e = (u >> 7) & 0xFF;
    c += (e >= 0x90);
  }
#pragma unroll
  for (int off = 32; off; off >>= 1) c += __shfl_xor(c, off);
  if ((t & 63) == 0) red[t >> 6] = c;
  __syncthreads();
  if (t == 0) flag[0] = (red[0] + red[1] + red[2] + red[3] >= 16) ? 1 : 0;
}

// ---------------------------------------------------------------------------
// Canonicalize 15 input slices to bf16 workspace copies (either src dtype).
// soff is an ELEMENT offset into the source.
// ---------------------------------------------------------------------------
struct Cvt {
  const void* s;
  u16* d;
  long soff;
  int n;
};
struct Cvt16 {
  Cvt c[15];
};
__global__ __launch_bounds__(256) void convert16(Cvt16 args, const int* __restrict__ flag) {
  const Cvt cc = args.c[blockIdx.y];
  const int i8 = (blockIdx.x * 256 + threadIdx.x) * 8;
  if (i8 >= cc.n) return;
  u16 o[8];
  if (flag[0]) {
    const float* s = (const float*)cc.s + cc.soff + i8;
    float4 a = *(const float4*)s;
    float4 b = *(const float4*)(s + 4);
    o[0] = f2b(a.x); o[1] = f2b(a.y); o[2] = f2b(a.z); o[3] = f2b(a.w);
    o[4] = f2b(b.x); o[5] = f2b(b.y); o[6] = f2b(b.z); o[7] = f2b(b.w);
  } else {
    uint4 r = *(const uint4*)((const u16*)cc.s + cc.soff + i8);
    __builtin_memcpy(o, &r, 16);
  }
  uint4 pk;
  __builtin_memcpy(&pk, o, 16);
  *(uint4*)(cc.d + i8) = pk;
}

// ---------------------------------------------------------------------------
// NT GEMM: C[z][m][n] = scale * sum_k A[z'][m][k] * B[z][n][k] (+ bias[n]).
// A offset: ((z>>zshA)&zmaskA)*sA elements. B: z*sB. C: base + z*sC (elems).
// OUT_BF16: 0=fp32, 1=bf16; oflag overrides (oflag[0]=1 -> fp32).
// DO_STATS: block-reduce sum/sum^2 of scaled C and atomicAdd to stats[z*2+.].
// 128x128 tile, BK=32, 256 thr = 4 waves, mfma_f32_16x16x32_bf16.
// ---------------------------------------------------------------------------
template <int OUT_BF16, int ADD_BIAS, int DO_STATS>
__global__ __launch_bounds__(256) void gemm_nt(
    const u16* __restrict__ A, const u16* __restrict__ B, void* __restrict__ Cv,
    const u16* __restrict__ bias, int lda, int ldb, int ldc, int K,
    long sA, int zshA, int zmaskA, long sB, long sC, long base, float scale,
    const int* __restrict__ oflag, float* __restrict__ stats) {
  __shared__ u16 As[128][40];
  __shared__ u16 Bs[128][40];
  __shared__ float redS[4], redQ[4];
  const int t = threadIdx.x;
  const int z = blockIdx.z;
  A += (long)((z >> zshA) & zmaskA) * sA;
  B += (long)z * sB;
  const int bm = blockIdx.y * 128;
  const int bn = blockIdx.x * 128;
  const int lane = t & 63;
  const int wv = t >> 6;
  const int wm = (wv & 1) * 64;
  const int wn = (wv >> 1) * 64;
  const int lr = lane & 15;
  const int lq = lane >> 4;
  const int m0 = t >> 2;
  const int kc = (t & 3) << 3;
  const u16* pa0 = A + (size_t)(bm + m0) * lda + kc;
  const u16* pa1 = pa0 + (size_t)64 * lda;
  const u16* pb0 = B + (size_t)(bn + m0) * ldb + kc;
  const u16* pb1 = pb0 + (size_t)64 * ldb;

  f32x4 acc[4][4];
#pragma unroll
  for (int i = 0; i < 4; i++)
#pragma unroll
    for (int j = 0; j < 4; j++) acc[i][j] = (f32x4){0.f, 0.f, 0.f, 0.f};

  for (int k0 = 0; k0 < K; k0 += 32) {
    uint4 a0 = *(const uint4*)(pa0 + k0);
    uint4 a1 = *(const uint4*)(pa1 + k0);
    uint4 b0 = *(const uint4*)(pb0 + k0);
    uint4 b1 = *(const uint4*)(pb1 + k0);
    *(uint4*)&As[m0][kc] = a0;
    *(uint4*)&As[m0 + 64][kc] = a1;
    *(uint4*)&Bs[m0][kc] = b0;
    *(uint4*)&Bs[m0 + 64][kc] = b1;
    __syncthreads();
    bf16x8 af[4], bfr[4];
#pragma unroll
    for (int i = 0; i < 4; i++) af[i] = *(const bf16x8*)&As[wm + i * 16 + lr][lq * 8];
#pragma unroll
    for (int j = 0; j < 4; j++) bfr[j] = *(const bf16x8*)&Bs[wn + j * 16 + lr][lq * 8];
#pragma unroll
    for (int i = 0; i < 4; i++)
#pragma unroll
      for (int j = 0; j < 4; j++)
        acc[i][j] = __builtin_amdgcn_mfma_f32_16x16x32_bf16(af[i], bfr[j], acc[i][j], 0, 0, 0);
    __syncthreads();
  }

  int f32o = OUT_BF16 ? 0 : 1;
  if (oflag) f32o = oflag[0];
  u16* Cb = (u16*)Cv + base + (long)z * sC;
  float* Cf = (float*)Cv + base + (long)z * sC;
  float ls = 0.f, lsq = 0.f;
#pragma unroll
  for (int i = 0; i < 4; i++) {
    const int gm0 = bm + wm + i * 16 + lq * 4;
#pragma unroll
    for (int j = 0; j < 4; j++) {
      const int gn = bn + wn + j * 16 + lr;
      float bv = 0.f;
      if (ADD_BIAS) bv = b2f(bias[gn]);
#pragma unroll
      for (int r = 0; r < 4; r++) {
        float v = acc[i][j][r] * scale + bv;
        if (DO_STATS) {
          ls += v;
          lsq += v * v;
        }
        if (f32o)
          Cf[(size_t)(gm0 + r) * ldc + gn] = v;
        else
          Cb[(size_t)(gm0 + r) * ldc + gn] = f2b(v);
      }
    }
  }
  if (DO_STATS) {
#pragma unroll
    for (int off = 32; off; off >>= 1) {
      ls += __shfl_xor(ls, off);
      lsq += __shfl_xor(lsq, off);
    }
    if (lane == 0) {
      redS[wv] = ls;
      redQ[wv] = lsq;
    }
    __syncthreads();
    if (t == 0) {
      atomicAdd(&stats[z * 2 + 0], redS[0] + redS[1] + redS[2] + redS[3]);
      atomicAdd(&stats[z * 2 + 1], redQ[0] + redQ[1] + redQ[2] + redQ[3]);
    }
  }
}

// ---------------------------------------------------------------------------
// InstanceNorm finalize: stats[z]={sum,sumsq} over 384*384 -> rstd[z]
// ---------------------------------------------------------------------------
__global__ __launch_bounds__(64) void finalize_stats(const float* __restrict__ stats,
                                                     float* __restrict__ rstd) {
  const int i = threadIdx.x;
  float s = stats[2 * i], q = stats[2 * i + 1];
  float mean = s * (1.f / 147456.f);
  float var = q * (1.f / 147456.f) - mean * mean;
  rstd[i] = 1.f / sqrtf(var + 1e-5f);
}

// ---------------------------------------------------------------------------
// Flag-aware batched transpose of the 4 embs: [br][b][384][1024] -> bf16
// xT [z=br*16+b][1024][384]. 64x64 LDS tiles. z = blockIdx.z.
// ---------------------------------------------------------------------------
struct Ptr4 {
  const void* p[4];
};
__global__ __launch_bounds__(256) void transpose_any4(Ptr4 in4, u16* __restrict__ out,
                                                      const int* __restrict__ flag) {
  __shared__ u16 tile[64][72];
  const int t = threadIdx.x;
  const int z = blockIdx.z;
  const int br = z >> 4, b = z & 15;
  const long ebase = (long)b * 393216;
  const int r0 = blockIdx.y * 64;
  const int c0 = blockIdx.x * 64;
  const int isf32 = flag[0];
#pragma unroll
  for (int j = 0; j < 2; j++) {
    int idx = t + 256 * j;
    int r = idx >> 3, c8 = (idx & 7) << 3;
    u16 v[8];
    if (isf32) {
      const float* in = (const float*)in4.p[br] + ebase + (size_t)(r0 + r) * 1024 + c0 + c8;
      float4 a = *(const float4*)in;
      float4 bb = *(const float4*)(in + 4);
      v[0] = f2b(a.x); v[1] = f2b(a.y); v[2] = f2b(a.z); v[3] = f2b(a.w);
      v[4] = f2b(bb.x); v[5] = f2b(bb.y); v[6] = f2b(bb.z); v[7] = f2b(bb.w);
    } else {
      const u16* in = (const u16*)in4.p[br] + ebase + (size_t)(r0 + r) * 1024 + c0 + c8;
      uint4 rr = *(const uint4*)in;
      __builtin_memcpy(v, &rr, 16);
    }
    __builtin_memcpy(&tile[r][c8], v, 16);
  }
  __syncthreads();
#pragma unroll
  for (int j = 0; j < 2; j++) {
    int idx = t + 256 * j;
    int c = idx >> 3, r8 = (idx & 7) << 3;
    u16 v[8];
#pragma unroll
    for (int jj = 0; jj < 8; jj++) v[jj] = tile[r8 + jj][c];
    uint4 pk;
    __builtin_memcpy(&pk, v, 16);
    *(uint4*)&out[(size_t)z * 393216 + (size_t)(c0 + c) * 384 + r0 + r8] = pk;
  }
}

// ---------------------------------------------------------------------------
// bf16 transpose: in [z][384][1024] -> out [z][1024][384]
// ---------------------------------------------------------------------------
__global__ __launch_bounds__(256) void transpose_bf16(const u16* __restrict__ in,
                                                      u16* __restrict__ out) {
  __shared__ u16 tile[64][72];
  const int t = threadIdx.x;
  in += (size_t)blockIdx.z * 393216;
  out += (size_t)blockIdx.z * 393216;
  const int r0 = blockIdx.y * 64;
  const int c0 = blockIdx.x * 64;
#pragma unroll
  for (int j = 0; j < 2; j++) {
    int idx = t + 256 * j;
    int r = idx >> 3, c8 = (idx & 7) << 3;
    *(uint4*)&tile[r][c8] = *(const uint4*)&in[(size_t)(r0 + r) * 1024 + c0 + c8];
  }
  __syncthreads();
#pragma unroll
  for (int j = 0; j < 2; j++) {
    int idx = t + 256 * j;
    int c = idx >> 3, r8 = (idx & 7) << 3;
    u16 v[8];
#pragma unroll
    for (int jj = 0; jj < 8; jj++) v[jj] = tile[r8 + jj][c];
    uint4 pk;
    __builtin_memcpy(&pk, v, 16);
    *(uint4*)&out[(size_t)(c0 + c) * 384 + r0 + r8] = pk;
  }
}

// ---------------------------------------------------------------------------
// In-place row L2-norm on bf16 [rows][1024] (torch F.normalize semantics)
// ---------------------------------------------------------------------------
__global__ __launch_bounds__(256) void l2norm_rows_bf16(u16* __restrict__ Q) {
  __shared__ float red[4];
  u16* row = Q + (size_t)blockIdx.x * 1024;
  const int t = threadIdx.x;
  uint2 r = *(const uint2*)(row + t * 4);
  u16 v[4];
  __builtin_memcpy(v, &r, 8);
  float f[4] = {b2f(v[0]), b2f(v[1]), b2f(v[2]), b2f(v[3])};
  float s = f[0] * f[0] + f[1] * f[1] + f[2] * f[2] + f[3] * f[3];
#pragma unroll
  for (int off = 32; off; off >>= 1) s += __shfl_xor(s, off);
  if ((t & 63) == 0) red[t >> 6] = s;
  __syncthreads();
  float tot = red[0] + red[1] + red[2] + red[3];
  float inv = 1.f / fmaxf(sqrtf(tot), 1e-12f);
  u16 o[4] = {f2b(f[0] * inv), f2b(f[1] * inv), f2b(f[2] * inv), f2b(f[3] * inv)};
  unsigned long long pk;
  __builtin_memcpy(&pk, o, 8);
  *(unsigned long long*)(row + t * 4) = pk;
}

// ---------------------------------------------------------------------------
// Grouped 3x3 conv (2 in / 2 out per group), SAME pad, 32x32 planes.
// grid (384, 16, 8); z: br=z>>1, kv=z&1. Input kvpre [br*16+b][768][1024]
// (rows 0-383=k_pre, 384-767=v_pre). kv==0 fuses row L2-norm.
// ---------------------------------------------------------------------------
__global__ __launch_bounds__(256) void gconv3x3(
    const u16* __restrict__ kvpre, const u16* __restrict__ kw,
    const u16* __restrict__ vw, u16* __restrict__ outK, u16* __restrict__ outV) {
  __shared__ float p[2][1024];
  __shared__ float red[4];
  const int o = blockIdx.x;
  const int b = blockIdx.y;
  const int br = blockIdx.z >> 1;
  const int kv = blockIdx.z & 1;
  const int t = threadIdx.x;
  const u16* in = kvpre + ((size_t)(br * 16 + b) * 768 + kv * 384 + (o & ~1)) * 1024;
  const u16* wp = (kv ? vw : kw) + br * 6912 + o * 18;
  u16* out = (kv ? outV : outK) + ((size_t)(br * 16 + b) * 384 + o) * 1024;
  {
    uint2 ra = *(const uint2*)(in + t * 4);
    uint2 rb = *(const uint2*)(in + 1024 + t * 4);
    u16 va[4], vb[4];
    __builtin_memcpy(va, &ra, 8);
    __builtin_memcpy(vb, &rb, 8);
#pragma unroll
    for (int j = 0; j < 4; j++) {
      p[0][t * 4 + j] = b2f(va[j]);
      p[1][t * 4 + j] = b2f(vb[j]);
    }
  }
  float w[18];
#pragma unroll
  for (int j = 0; j < 18; j++) w[j] = b2f(wp[j]);
  __syncthreads();
  float o4[4];
#pragma unroll
  for (int ii = 0; ii < 4; ii++) {
    const int pidx = t + 256 * ii;
    const int y = pidx >> 5, x = pidx & 31;
    float acc = 0.f;
#pragma unroll
    for (int ch = 0; ch < 2; ch++)
#pragma unroll
      for (int dy = 0; dy < 3; dy++) {
        const int yy = y + dy - 1;
        if (yy < 0 || yy > 31) continue;
#pragma unroll
        for (int dx = 0; dx < 3; dx++) {
          const int xx = x + dx - 1;
          if (xx < 0 || xx > 31) continue;
          acc += w[ch * 9 + dy * 3 + dx] * p[ch][yy * 32 + xx];
        }
      }
    o4[ii] = acc;
  }
  float inv = 1.f;
  if (kv == 0) {
    float s = o4[0] * o4[0] + o4[1] * o4[1] + o4[2] * o4[2] + o4[3] * o4[3];
#pragma unroll
    for (int off = 32; off; off >>= 1) s += __shfl_xor(s, off);
    if ((t & 63) == 0) red[t >> 6] = s;
    __syncthreads();
    float tot = red[0] + red[1] + red[2] + red[3];
    inv = 1.f / fmaxf(sqrtf(tot), 1e-12f);
  }
#pragma unroll
  for (int ii = 0; ii < 4; ii++) out[t + 256 * ii] = f2b(o4[ii] * inv);
}

// ---------------------------------------------------------------------------
// Softmax over rows of 384 after inst-norm scale (mean cancels). 1 wave/row.
// S: [z=0..63][384][384]; rstd per z.
// ---------------------------------------------------------------------------
__global__ __launch_bounds__(256) void softmax384(const float* __restrict__ S,
                                                  const float* __restrict__ rstdA,
                                                  u16* __restrict__ P) {
  const int row = blockIdx.x * 4 + (threadIdx.x >> 6);
  const int lane = threadIdx.x & 63;
  const float rstd = rstdA[row / 384];
  const float* x = S + (size_t)row * 384;
  float v[6];
#pragma unroll
  for (int j = 0; j < 6; j++) v[j] = x[lane + 64 * j] * rstd;
  float m = v[0];
#pragma unroll
  for (int j = 1; j < 6; j++) m = fmaxf(m, v[j]);
#pragma unroll
  for (int off = 32; off; off >>= 1) m = fmaxf(m, __shfl_xor(m, off));
  float s = 0.f;
#pragma unroll
  for (int j = 0; j < 6; j++) {
    v[j] = __expf(v[j] - m);
    s += v[j];
  }
#pragma unroll
  for (int off = 32; off; off >>= 1) s += __shfl_xor(s, off);
  const float inv = 1.f / s;
  u16* out = P + (size_t)row * 384;
#pragma unroll
  for (int j = 0; j < 6; j++) out[lane + 64 * j] = f2b(v[j] * inv);
}

// ---------------------------------------------------------------------------
// B=16, C=384, H=W=32, HW=1024, TEXT=768. ws usage ~278 MB (ws is 384 MiB).
// ---------------------------------------------------------------------------
extern "C" void kernel_launch(void* const* d_in, const int* in_sizes, int n_in,
                              void* d_out, int out_size, void* d_ws, size_t ws_size,
                              hipStream_t stream) {
  (void)in_sizes; (void)n_in; (void)out_size; (void)ws_size;
  char* ws = (char*)d_ws;

  int* flag = (int*)ws;
  float* stats = (float*)(ws + 256);  // 128 floats: [64]{sum,sumsq}
  float* rstd = (float*)(ws + 1024);  // 64 floats
  char* wgt = ws + 2048;
  u16* wq16 = (u16*)wgt;                  // 1572864 B
  u16* bq16 = (u16*)(wgt + 1572864);      // 2048 B
  u16* mkv16 = (u16*)(wgt + 1574912);     // [4][768][384] = 2359296 B
  u16* kw16 = (u16*)(wgt + 3934208);      // 55296 B
  u16* vw16 = (u16*)(wgt + 3989504);      // 55296 B
  u16* po16 = (u16*)(wgt + 4044800);      // 1179648 B
  char* big = ws + 8388608;
  u16* q16 = (u16*)big;                        // 12582912 B, persistent
  u16* bufA = (u16*)(big + 12582912);          // 50331648 B: xT -> kAll
  u16* bufB = (u16*)(big + 62914560);          // 100663296 B: kvpre -> O|OT
  u16* bufC = (u16*)(big + 163577856);         // 50331648 B: text16 -> vAll -> S
  u16* bufD = (u16*)(big + 213909504);         // 50331648 B: vT
  u16* bufE = (u16*)(big + 264241152);         // 18874368 B: P16
  u16* text16 = bufC;
  u16* xT = bufA;
  u16* kvpre = bufB;
  u16* kAll = bufA;
  u16* vAll = bufC;
  u16* vT = bufD;
  float* S = (float*)bufC;   // 37748736 B
  u16* P16 = bufE;
  u16* O = bufB;
  u16* OT = (u16*)((char*)bufB + 50331648);

  const dim3 blk(256);
  const float scale = 0.05103103630798288f;  // 1/sqrt(384)

  detect_dtype<<<1, blk, 0, stream>>>((const u16*)d_in[4], flag, stats);

  // 15 conversion slices. mkv16 per-branch stride = 294912 ELEMENTS
  // ([mk_i;mv_i] = 768*384).
  Cvt16 ca;
  int ci = 0;
  auto add = [&](const void* s, u16* d, long soff, int n) {
    ca.c[ci].s = s; ca.c[ci].d = d; ca.c[ci].soff = soff; ca.c[ci].n = n; ci++;
  };
  add(d_in[4], text16, 0, 4718592);
  add(d_in[5], wq16, 0, 786432);
  add(d_in[6], bq16, 0, 1024);
  for (int i = 0; i < 4; i++) add(d_in[7], mkv16 + (long)i * 294912, (long)i * 147456, 147456);
  for (int i = 0; i < 4; i++) add(d_in[8], mkv16 + (long)i * 294912 + 147456, (long)i * 147456, 147456);
  add(d_in[9], kw16, 0, 27648);
  add(d_in[10], vw16, 0, 27648);
  add(d_in[11], po16, 0, 589824);
  convert16<<<dim3(2304, 15, 1), blk, 0, stream>>>(ca, flag);

  // q = l2norm(text @ wq^T + bq): M=6144, N=1024, K=768
  gemm_nt<1, 1, 0><<<dim3(8, 48, 1), blk, 0, stream>>>(
      text16, wq16, q16, bq16, 768, 768, 1024, 768, 0, 0, 0, 0, 0, 0, 1.f,
      nullptr, nullptr);
  l2norm_rows_bf16<<<6144, blk, 0, stream>>>(q16);

  // xT[z] = emb[br][b]^T for all 64 z
  Ptr4 p4 = {{d_in[0], d_in[1], d_in[2], d_in[3]}};
  transpose_any4<<<dim3(16, 6, 64), blk, 0, stream>>>(p4, xT, flag);

  // kvpre[z] = [mk_br; mv_br] @ x[z] : M=768, N=1024, K=384
  gemm_nt<1, 0, 0><<<dim3(8, 6, 64), blk, 0, stream>>>(
      mkv16, xT, kvpre, nullptr, 384, 384, 1024, 384, 294912, 4, 3, 393216,
      786432, 0, 1.f, nullptr, nullptr);

  // grouped 3x3 conv, all branches; k gets fused row L2-norm
  gconv3x3<<<dim3(384, 16, 8), blk, 0, stream>>>(kvpre, kw16, vw16, kAll, vAll);

  // vT[z] = v[z]^T
  transpose_bf16<<<dim3(16, 6, 64), blk, 0, stream>>>(vAll, vT);

  // S[z] = scale * q[b] @ k[z]^T (M=N=384, K=1024) + fused inst-norm stats
  gemm_nt<0, 0, 1><<<dim3(3, 3, 64), blk, 0, stream>>>(
      q16, kAll, S, nullptr, 1024, 1024, 384, 1024, 393216, 0, 15, 393216,
      147456, 0, scale, nullptr, stats);
  finalize_stats<<<1, 64, 0, stream>>>(stats, rstd);
  softmax384<<<6144, blk, 0, stream>>>(S, rstd, P16);

  // O[z] = P[z] @ v[z] : M=384, N=1024, K=384 (B=vT)
  gemm_nt<1, 0, 0><<<dim3(8, 3, 64), blk, 0, stream>>>(
      P16, vT, O, nullptr, 384, 384, 1024, 384, 147456, 0, 63, 393216, 393216,
      0, 1.f, nullptr, nullptr);
  transpose_bf16<<<dim3(16, 6, 64), blk, 0, stream>>>(O, OT);

  // out[z] = po_br @ O[z] : M=384, N=1024, K=384 (B=OT); dtype per flag
  gemm_nt<0, 0, 0><<<dim3(8, 3, 64), blk, 0, stream>>>(
      po16, OT, d_out, nullptr, 384, 384, 1024, 384, 147456, 4, 3, 393216,
      393216, 0, 1.f, flag, nullptr);
}

// Round 7
// 602.548 us; speedup vs baseline: 1.7078x; 1.0244x over previous
//
#include <hip/hip_runtime.h>

typedef unsigned short u16;
typedef __bf16 bf16x8 __attribute__((ext_vector_type(8)));
typedef float f32x4 __attribute__((ext_vector_type(4)));

__device__ __forceinline__ float b2f(u16 u) {
  unsigned int x = ((unsigned int)u) << 16;
  float f;
  __builtin_memcpy(&f, &x, 4);
  return f;
}
__device__ __forceinline__ u16 f2b(float f) {
  unsigned int x;
  __builtin_memcpy(&x, &f, 4);
  unsigned int r = x + 0x7FFFu + ((x >> 16) & 1u);
  return (u16)(r >> 16);
}

// Async global->LDS, 16B per lane. LDS dest = wave-uniform base + lane*16.
__device__ __forceinline__ void gl_lds16(const u16* g, u16* l) {
  __builtin_amdgcn_global_load_lds(
      (const __attribute__((address_space(1))) void*)g,
      (__attribute__((address_space(3))) void*)l, 16, 0, 0);
}

// ---------------------------------------------------------------------------
// Dtype sniff (bf16 N(0,1) never has exponent>=0x90; fp32-as-u16 does ~44%)
// + zero the stats accumulators (ws is 0xAA-poisoned before every call).
// ---------------------------------------------------------------------------
__global__ __launch_bounds__(256) void detect_dtype(const u16* __restrict__ text,
                                                    int* __restrict__ flag,
                                                    float* __restrict__ stats) {
  __shared__ int red[4];
  const int t = threadIdx.x;
  if (t < 128) stats[t] = 0.f;
  int c = 0;
#pragma unroll
  for (int j = 0; j < 8; j++) {
    u16 u = text[t * 8 + j];
    int e = (u >> 7) & 0xFF;
    c += (e >= 0x90);
  }
#pragma unroll
  for (int off = 32; off; off >>= 1) c += __shfl_xor(c, off);
  if ((t & 63) == 0) red[t >> 6] = c;
  __syncthreads();
  if (t == 0) flag[0] = (red[0] + red[1] + red[2] + red[3] >= 16) ? 1 : 0;
}

// ---------------------------------------------------------------------------
// Canonicalize 15 input slices to bf16 workspace copies (either src dtype).
// ---------------------------------------------------------------------------
struct Cvt {
  const void* s;
  u16* d;
  long soff;
  int n;
};
struct Cvt16 {
  Cvt c[15];
};
__global__ __launch_bounds__(256) void convert16(Cvt16 args, const int* __restrict__ flag) {
  const Cvt cc = args.c[blockIdx.y];
  const int i8 = (blockIdx.x * 256 + threadIdx.x) * 8;
  if (i8 >= cc.n) return;
  u16 o[8];
  if (flag[0]) {
    const float* s = (const float*)cc.s + cc.soff + i8;
    float4 a = *(const float4*)s;
    float4 b = *(const float4*)(s + 4);
    o[0] = f2b(a.x); o[1] = f2b(a.y); o[2] = f2b(a.z); o[3] = f2b(a.w);
    o[4] = f2b(b.x); o[5] = f2b(b.y); o[6] = f2b(b.z); o[7] = f2b(b.w);
  } else {
    uint4 r = *(const uint4*)((const u16*)cc.s + cc.soff + i8);
    __builtin_memcpy(o, &r, 16);
  }
  uint4 pk;
  __builtin_memcpy(&pk, o, 16);
  *(uint4*)(cc.d + i8) = pk;
}

// ---------------------------------------------------------------------------
// NT GEMM: C[z][m][n] = scale * sum_k A[z'][m][k] * B[z][n][k] (+ bias[n]).
// A offset: ((z>>zshA)&zmaskA)*sA elements. B: z*sB. C: base + z*sC (elems).
// Staging: global_load_lds width=16 into a unit-swizzled LDS tile.
//   Tile = 128 rows x 32 k (u16) = 512 x 16B units.
//   Unit (m,kc) lives at slot m*4 + ((kc + ((m>>1)&3)) & 3)  [kc = k/8].
//   Load: chunk c (16 rows), lane l fetches global (row=c*16+(l>>2),
//         kc=((l&3)-((l>>3)&3))&3) -> slot c*64+l. Coalescing preserved
//         (within-64B permutation); fragment ds_read_b128 is 2-way max.
// 128x128 tile, BK=32, 256 thr = 4 waves, mfma_f32_16x16x32_bf16.
// ---------------------------------------------------------------------------
template <int OUT_BF16, int ADD_BIAS, int DO_STATS>
__global__ __launch_bounds__(256) void gemm_nt(
    const u16* __restrict__ A, const u16* __restrict__ B, void* __restrict__ Cv,
    const u16* __restrict__ bias, int lda, int ldb, int ldc, int K,
    long sA, int zshA, int zmaskA, long sB, long sC, long base, float scale,
    const int* __restrict__ oflag, float* __restrict__ stats) {
  __shared__ u16 As[4096];
  __shared__ u16 Bs[4096];
  __shared__ float redS[4], redQ[4];
  const int t = threadIdx.x;
  const int z = blockIdx.z;
  A += (long)((z >> zshA) & zmaskA) * sA;
  B += (long)z * sB;
  const int bm = blockIdx.y * 128;
  const int bn = blockIdx.x * 128;
  const int lane = t & 63;
  const int wv = t >> 6;
  const int wm = (wv & 1) * 64;
  const int wn = (wv >> 1) * 64;
  const int lr = lane & 15;
  const int lq = lane >> 4;

  // staging addresses: wave wv handles chunks c0=2*wv and c0+1 of both tiles
  const int c0 = wv * 2;
  const int row0 = c0 * 16 + (lane >> 2);
  const int kcl = (((lane & 3) - ((lane >> 3) & 3)) & 3) * 8;
  const u16* pa0 = A + (size_t)(bm + row0) * lda + kcl;
  const u16* pa1 = pa0 + (size_t)16 * lda;
  const u16* pb0 = B + (size_t)(bn + row0) * ldb + kcl;
  const u16* pb1 = pb0 + (size_t)16 * ldb;
  u16* lA0 = &As[c0 * 512];
  u16* lA1 = &As[c0 * 512 + 512];
  u16* lB0 = &Bs[c0 * 512];
  u16* lB1 = &Bs[c0 * 512 + 512];

  // fragment LDS addresses (K-invariant)
  const u16* aptr[4];
  const u16* bptr[4];
#pragma unroll
  for (int i = 0; i < 4; i++) {
    const int m = wm + i * 16 + lr;
    aptr[i] = &As[(m * 4 + ((lq + ((m >> 1) & 3)) & 3)) * 8];
    const int n = wn + i * 16 + lr;
    bptr[i] = &Bs[(n * 4 + ((lq + ((n >> 1) & 3)) & 3)) * 8];
  }

  f32x4 acc[4][4];
#pragma unroll
  for (int i = 0; i < 4; i++)
#pragma unroll
    for (int j = 0; j < 4; j++) acc[i][j] = (f32x4){0.f, 0.f, 0.f, 0.f};

  for (int k0 = 0; k0 < K; k0 += 32) {
    gl_lds16(pa0 + k0, lA0);
    gl_lds16(pa1 + k0, lA1);
    gl_lds16(pb0 + k0, lB0);
    gl_lds16(pb1 + k0, lB1);
    __syncthreads();
    bf16x8 af[4], bfr[4];
#pragma unroll
    for (int i = 0; i < 4; i++) af[i] = *(const bf16x8*)aptr[i];
#pragma unroll
    for (int j = 0; j < 4; j++) bfr[j] = *(const bf16x8*)bptr[j];
#pragma unroll
    for (int i = 0; i < 4; i++)
#pragma unroll
      for (int j = 0; j < 4; j++)
        acc[i][j] = __builtin_amdgcn_mfma_f32_16x16x32_bf16(af[i], bfr[j], acc[i][j], 0, 0, 0);
    __syncthreads();
  }

  int f32o = OUT_BF16 ? 0 : 1;
  if (oflag) f32o = oflag[0];
  u16* Cb = (u16*)Cv + base + (long)z * sC;
  float* Cf = (float*)Cv + base + (long)z * sC;
  float ls = 0.f, lsq = 0.f;
#pragma unroll
  for (int i = 0; i < 4; i++) {
    const int gm0 = bm + wm + i * 16 + lq * 4;
#pragma unroll
    for (int j = 0; j < 4; j++) {
      const int gn = bn + wn + j * 16 + lr;
      float bv = 0.f;
      if (ADD_BIAS) bv = b2f(bias[gn]);
#pragma unroll
      for (int r = 0; r < 4; r++) {
        float v = acc[i][j][r] * scale + bv;
        if (DO_STATS) {
          ls += v;
          lsq += v * v;
        }
        if (f32o)
          Cf[(size_t)(gm0 + r) * ldc + gn] = v;
        else
          Cb[(size_t)(gm0 + r) * ldc + gn] = f2b(v);
      }
    }
  }
  if (DO_STATS) {
#pragma unroll
    for (int off = 32; off; off >>= 1) {
      ls += __shfl_xor(ls, off);
      lsq += __shfl_xor(lsq, off);
    }
    if (lane == 0) {
      redS[wv] = ls;
      redQ[wv] = lsq;
    }
    __syncthreads();
    if (t == 0) {
      atomicAdd(&stats[z * 2 + 0], redS[0] + redS[1] + redS[2] + redS[3]);
      atomicAdd(&stats[z * 2 + 1], redQ[0] + redQ[1] + redQ[2] + redQ[3]);
    }
  }
}

// ---------------------------------------------------------------------------
// InstanceNorm finalize: stats[z]={sum,sumsq} over 384*384 -> rstd[z]
// ---------------------------------------------------------------------------
__global__ __launch_bounds__(64) void finalize_stats(const float* __restrict__ stats,
                                                     float* __restrict__ rstd) {
  const int i = threadIdx.x;
  float s = stats[2 * i], q = stats[2 * i + 1];
  float mean = s * (1.f / 147456.f);
  float var = q * (1.f / 147456.f) - mean * mean;
  rstd[i] = 1.f / sqrtf(var + 1e-5f);
}

// ---------------------------------------------------------------------------
// Flag-aware batched transpose of the 4 embs: [br][b][384][1024] -> bf16
// xT [z=br*16+b][1024][384]. 64x64 LDS tiles. z = blockIdx.z.
// ---------------------------------------------------------------------------
struct Ptr4 {
  const void* p[4];
};
__global__ __launch_bounds__(256) void transpose_any4(Ptr4 in4, u16* __restrict__ out,
                                                      const int* __restrict__ flag) {
  __shared__ u16 tile[64][72];
  const int t = threadIdx.x;
  const int z = blockIdx.z;
  const int br = z >> 4, b = z & 15;
  const long ebase = (long)b * 393216;
  const int r0 = blockIdx.y * 64;
  const int c0 = blockIdx.x * 64;
  const int isf32 = flag[0];
#pragma unroll
  for (int j = 0; j < 2; j++) {
    int idx = t + 256 * j;
    int r = idx >> 3, c8 = (idx & 7) << 3;
    u16 v[8];
    if (isf32) {
      const float* in = (const float*)in4.p[br] + ebase + (size_t)(r0 + r) * 1024 + c0 + c8;
      float4 a = *(const float4*)in;
      float4 bb = *(const float4*)(in + 4);
      v[0] = f2b(a.x); v[1] = f2b(a.y); v[2] = f2b(a.z); v[3] = f2b(a.w);
      v[4] = f2b(bb.x); v[5] = f2b(bb.y); v[6] = f2b(bb.z); v[7] = f2b(bb.w);
    } else {
      const u16* in = (const u16*)in4.p[br] + ebase + (size_t)(r0 + r) * 1024 + c0 + c8;
      uint4 rr = *(const uint4*)in;
      __builtin_memcpy(v, &rr, 16);
    }
    __builtin_memcpy(&tile[r][c8], v, 16);
  }
  __syncthreads();
#pragma unroll
  for (int j = 0; j < 2; j++) {
    int idx = t + 256 * j;
    int c = idx >> 3, r8 = (idx & 7) << 3;
    u16 v[8];
#pragma unroll
    for (int jj = 0; jj < 8; jj++) v[jj] = tile[r8 + jj][c];
    uint4 pk;
    __builtin_memcpy(&pk, v, 16);
    *(uint4*)&out[(size_t)z * 393216 + (size_t)(c0 + c) * 384 + r0 + r8] = pk;
  }
}

// ---------------------------------------------------------------------------
// bf16 transpose: in [z][384][1024] -> out [z][1024][384]
// ---------------------------------------------------------------------------
__global__ __launch_bounds__(256) void transpose_bf16(const u16* __restrict__ in,
                                                      u16* __restrict__ out) {
  __shared__ u16 tile[64][72];
  const int t = threadIdx.x;
  in += (size_t)blockIdx.z * 393216;
  out += (size_t)blockIdx.z * 393216;
  const int r0 = blockIdx.y * 64;
  const int c0 = blockIdx.x * 64;
#pragma unroll
  for (int j = 0; j < 2; j++) {
    int idx = t + 256 * j;
    int r = idx >> 3, c8 = (idx & 7) << 3;
    *(uint4*)&tile[r][c8] = *(const uint4*)&in[(size_t)(r0 + r) * 1024 + c0 + c8];
  }
  __syncthreads();
#pragma unroll
  for (int j = 0; j < 2; j++) {
    int idx = t + 256 * j;
    int c = idx >> 3, r8 = (idx & 7) << 3;
    u16 v[8];
#pragma unroll
    for (int jj = 0; jj < 8; jj++) v[jj] = tile[r8 + jj][c];
    uint4 pk;
    __builtin_memcpy(&pk, v, 16);
    *(uint4*)&out[(size_t)(c0 + c) * 384 + r0 + r8] = pk;
  }
}

// ---------------------------------------------------------------------------
// In-place row L2-norm on bf16 [rows][1024] (torch F.normalize semantics)
// ---------------------------------------------------------------------------
__global__ __launch_bounds__(256) void l2norm_rows_bf16(u16* __restrict__ Q) {
  __shared__ float red[4];
  u16* row = Q + (size_t)blockIdx.x * 1024;
  const int t = threadIdx.x;
  uint2 r = *(const uint2*)(row + t * 4);
  u16 v[4];
  __builtin_memcpy(v, &r, 8);
  float f[4] = {b2f(v[0]), b2f(v[1]), b2f(v[2]), b2f(v[3])};
  float s = f[0] * f[0] + f[1] * f[1] + f[2] * f[2] + f[3] * f[3];
#pragma unroll
  for (int off = 32; off; off >>= 1) s += __shfl_xor(s, off);
  if ((t & 63) == 0) red[t >> 6] = s;
  __syncthreads();
  float tot = red[0] + red[1] + red[2] + red[3];
  float inv = 1.f / fmaxf(sqrtf(tot), 1e-12f);
  u16 o[4] = {f2b(f[0] * inv), f2b(f[1] * inv), f2b(f[2] * inv), f2b(f[3] * inv)};
  unsigned long long pk;
  __builtin_memcpy(&pk, o, 8);
  *(unsigned long long*)(row + t * 4) = pk;
}

// ---------------------------------------------------------------------------
// Grouped 3x3 conv (2 in / 2 out per group), SAME pad, 32x32 planes.
// grid (384, 16, 8); z: br=z>>1, kv=z&1. Input kvpre [br*16+b][768][1024]
// (rows 0-383=k_pre, 384-767=v_pre). kv==0 fuses row L2-norm.
// ---------------------------------------------------------------------------
__global__ __launch_bounds__(256) void gconv3x3(
    const u16* __restrict__ kvpre, const u16* __restrict__ kw,
    const u16* __restrict__ vw, u16* __restrict__ outK, u16* __restrict__ outV) {
  __shared__ float p[2][1024];
  __shared__ float red[4];
  const int o = blockIdx.x;
  const int b = blockIdx.y;
  const int br = blockIdx.z >> 1;
  const int kv = blockIdx.z & 1;
  const int t = threadIdx.x;
  const u16* in = kvpre + ((size_t)(br * 16 + b) * 768 + kv * 384 + (o & ~1)) * 1024;
  const u16* wp = (kv ? vw : kw) + br * 6912 + o * 18;
  u16* out = (kv ? outV : outK) + ((size_t)(br * 16 + b) * 384 + o) * 1024;
  {
    uint2 ra = *(const uint2*)(in + t * 4);
    uint2 rb = *(const uint2*)(in + 1024 + t * 4);
    u16 va[4], vb[4];
    __builtin_memcpy(va, &ra, 8);
    __builtin_memcpy(vb, &rb, 8);
#pragma unroll
    for (int j = 0; j < 4; j++) {
      p[0][t * 4 + j] = b2f(va[j]);
      p[1][t * 4 + j] = b2f(vb[j]);
    }
  }
  float w[18];
#pragma unroll
  for (int j = 0; j < 18; j++) w[j] = b2f(wp[j]);
  __syncthreads();
  float o4[4];
#pragma unroll
  for (int ii = 0; ii < 4; ii++) {
    const int pidx = t + 256 * ii;
    const int y = pidx >> 5, x = pidx & 31;
    float acc = 0.f;
#pragma unroll
    for (int ch = 0; ch < 2; ch++)
#pragma unroll
      for (int dy = 0; dy < 3; dy++) {
        const int yy = y + dy - 1;
        if (yy < 0 || yy > 31) continue;
#pragma unroll
        for (int dx = 0; dx < 3; dx++) {
          const int xx = x + dx - 1;
          if (xx < 0 || xx > 31) continue;
          acc += w[ch * 9 + dy * 3 + dx] * p[ch][yy * 32 + xx];
        }
      }
    o4[ii] = acc;
  }
  float inv = 1.f;
  if (kv == 0) {
    float s = o4[0] * o4[0] + o4[1] * o4[1] + o4[2] * o4[2] + o4[3] * o4[3];
#pragma unroll
    for (int off = 32; off; off >>= 1) s += __shfl_xor(s, off);
    if ((t & 63) == 0) red[t >> 6] = s;
    __syncthreads();
    float tot = red[0] + red[1] + red[2] + red[3];
    inv = 1.f / fmaxf(sqrtf(tot), 1e-12f);
  }
#pragma unroll
  for (int ii = 0; ii < 4; ii++) out[t + 256 * ii] = f2b(o4[ii] * inv);
}

// ---------------------------------------------------------------------------
// Softmax over rows of 384 after inst-norm scale (mean cancels). 1 wave/row.
// ---------------------------------------------------------------------------
__global__ __launch_bounds__(256) void softmax384(const float* __restrict__ S,
                                                  const float* __restrict__ rstdA,
                                                  u16* __restrict__ P) {
  const int row = blockIdx.x * 4 + (threadIdx.x >> 6);
  const int lane = threadIdx.x & 63;
  const float rstd = rstdA[row / 384];
  const float* x = S + (size_t)row * 384;
  float v[6];
#pragma unroll
  for (int j = 0; j < 6; j++) v[j] = x[lane + 64 * j] * rstd;
  float m = v[0];
#pragma unroll
  for (int j = 1; j < 6; j++) m = fmaxf(m, v[j]);
#pragma unroll
  for (int off = 32; off; off >>= 1) m = fmaxf(m, __shfl_xor(m, off));
  float s = 0.f;
#pragma unroll
  for (int j = 0; j < 6; j++) {
    v[j] = __expf(v[j] - m);
    s += v[j];
  }
#pragma unroll
  for (int off = 32; off; off >>= 1) s += __shfl_xor(s, off);
  const float inv = 1.f / s;
  u16* out = P + (size_t)row * 384;
#pragma unroll
  for (int j = 0; j < 6; j++) out[lane + 64 * j] = f2b(v[j] * inv);
}

// ---------------------------------------------------------------------------
// B=16, C=384, H=W=32, HW=1024, TEXT=768. ws usage ~278 MB (ws is 384 MiB).
// ---------------------------------------------------------------------------
extern "C" void kernel_launch(void* const* d_in, const int* in_sizes, int n_in,
                              void* d_out, int out_size, void* d_ws, size_t ws_size,
                              hipStream_t stream) {
  (void)in_sizes; (void)n_in; (void)out_size; (void)ws_size;
  char* ws = (char*)d_ws;

  int* flag = (int*)ws;
  float* stats = (float*)(ws + 256);  // 128 floats: [64]{sum,sumsq}
  float* rstd = (float*)(ws + 1024);  // 64 floats
  char* wgt = ws + 2048;
  u16* wq16 = (u16*)wgt;                  // 1572864 B
  u16* bq16 = (u16*)(wgt + 1572864);      // 2048 B
  u16* mkv16 = (u16*)(wgt + 1574912);     // [4][768][384] = 2359296 B
  u16* kw16 = (u16*)(wgt + 3934208);      // 55296 B
  u16* vw16 = (u16*)(wgt + 3989504);      // 55296 B
  u16* po16 = (u16*)(wgt + 4044800);      // 1179648 B
  char* big = ws + 8388608;
  u16* q16 = (u16*)big;                        // 12582912 B, persistent
  u16* bufA = (u16*)(big + 12582912);          // 50331648 B: xT -> kAll
  u16* bufB = (u16*)(big + 62914560);          // 100663296 B: kvpre -> O|OT
  u16* bufC = (u16*)(big + 163577856);         // 50331648 B: text16 -> vAll -> S
  u16* bufD = (u16*)(big + 213909504);         // 50331648 B: vT
  u16* bufE = (u16*)(big + 264241152);         // 18874368 B: P16
  u16* text16 = bufC;
  u16* xT = bufA;
  u16* kvpre = bufB;
  u16* kAll = bufA;
  u16* vAll = bufC;
  u16* vT = bufD;
  float* S = (float*)bufC;   // 37748736 B
  u16* P16 = bufE;
  u16* O = bufB;
  u16* OT = (u16*)((char*)bufB + 50331648);

  const dim3 blk(256);
  const float scale = 0.05103103630798288f;  // 1/sqrt(384)

  detect_dtype<<<1, blk, 0, stream>>>((const u16*)d_in[4], flag, stats);

  // 15 conversion slices. mkv16 per-branch stride = 294912 ELEMENTS.
  Cvt16 ca;
  int ci = 0;
  auto add = [&](const void* s, u16* d, long soff, int n) {
    ca.c[ci].s = s; ca.c[ci].d = d; ca.c[ci].soff = soff; ca.c[ci].n = n; ci++;
  };
  add(d_in[4], text16, 0, 4718592);
  add(d_in[5], wq16, 0, 786432);
  add(d_in[6], bq16, 0, 1024);
  for (int i = 0; i < 4; i++) add(d_in[7], mkv16 + (long)i * 294912, (long)i * 147456, 147456);
  for (int i = 0; i < 4; i++) add(d_in[8], mkv16 + (long)i * 294912 + 147456, (long)i * 147456, 147456);
  add(d_in[9], kw16, 0, 27648);
  add(d_in[10], vw16, 0, 27648);
  add(d_in[11], po16, 0, 589824);
  convert16<<<dim3(2304, 15, 1), blk, 0, stream>>>(ca, flag);

  // q = l2norm(text @ wq^T + bq): M=6144, N=1024, K=768
  gemm_nt<1, 1, 0><<<dim3(8, 48, 1), blk, 0, stream>>>(
      text16, wq16, q16, bq16, 768, 768, 1024, 768, 0, 0, 0, 0, 0, 0, 1.f,
      nullptr, nullptr);
  l2norm_rows_bf16<<<6144, blk, 0, stream>>>(q16);

  // xT[z] = emb[br][b]^T for all 64 z
  Ptr4 p4 = {{d_in[0], d_in[1], d_in[2], d_in[3]}};
  transpose_any4<<<dim3(16, 6, 64), blk, 0, stream>>>(p4, xT, flag);

  // kvpre[z] = [mk_br; mv_br] @ x[z] : M=768, N=1024, K=384
  gemm_nt<1, 0, 0><<<dim3(8, 6, 64), blk, 0, stream>>>(
      mkv16, xT, kvpre, nullptr, 384, 384, 1024, 384, 294912, 4, 3, 393216,
      786432, 0, 1.f, nullptr, nullptr);

  // grouped 3x3 conv, all branches; k gets fused row L2-norm
  gconv3x3<<<dim3(384, 16, 8), blk, 0, stream>>>(kvpre, kw16, vw16, kAll, vAll);

  // vT[z] = v[z]^T
  transpose_bf16<<<dim3(16, 6, 64), blk, 0, stream>>>(vAll, vT);

  // S[z] = scale * q[b] @ k[z]^T (M=N=384, K=1024) + fused inst-norm stats
  gemm_nt<0, 0, 1><<<dim3(3, 3, 64), blk, 0, stream>>>(
      q16, kAll, S, nullptr, 1024, 1024, 384, 1024, 393216, 0, 15, 393216,
      147456, 0, scale, nullptr, stats);
  finalize_stats<<<1, 64, 0, stream>>>(stats, rstd);
  softmax384<<<6144, blk, 0, stream>>>(S, rstd, P16);

  // O[z] = P[z] @ v[z] : M=384, N=1024, K=384 (B=vT)
  gemm_nt<1, 0, 0><<<dim3(8, 3, 64), blk, 0, stream>>>(
      P16, vT, O, nullptr, 384, 384, 1024, 384, 147456, 0, 63, 393216, 393216,
      0, 1.f, nullptr, nullptr);
  transpose_bf16<<<dim3(16, 6, 64), blk, 0, stream>>>(O, OT);

  // out[z] = po_br @ O[z] : M=384, N=1024, K=384 (B=OT); dtype per flag
  gemm_nt<0, 0, 0><<<dim3(8, 3, 64), blk, 0, stream>>>(
      po16, OT, d_out, nullptr, 384, 384, 1024, 384, 147456, 4, 3, 393216,
      393216, 0, 1.f, flag, nullptr);
}